// Round 5
// baseline (1635.452 us; speedup 1.0000x reference)
//
#include <hip/hip_runtime.h>
#include <hip/hip_bf16.h>
#include <cstdint>
#include <cstddef>

#define DEVI __device__ __forceinline__

typedef unsigned short u16;
using frag_ab = __attribute__((ext_vector_type(8))) short;   // 8 bf16 (4 VGPRs)
using f32x4   = __attribute__((ext_vector_type(4))) float;   // mfma acc

constexpr int HW = 16384;   // 128*128 spatial
constexpr int NC = 256;     // channels (Cin = Cout = 256)

DEVI u16 bf16bits(float f) {
    union { float f; uint32_t u; } cv; cv.f = f;
    uint32_t u = cv.u;
    u += 0x7fffu + ((u >> 16) & 1u);   // RNE
    return (u16)(u >> 16);
}

DEVI void gload16(const void* g, void* l) {
    __builtin_amdgcn_global_load_lds(
        (const __attribute__((address_space(1))) uint32_t*)g,
        (__attribute__((address_space(3))) uint32_t*)l, 16, 0, 0);
}

// LDS slab: [row][64B]; 16B slot s at phys slot s ^ (row&3) ^ ((row>>2)&3).
// Staging fetches pre-swizzled global slot (m173); frag reads use matching phys.
DEVI frag_ab read_frag(const u16* slab, int row, int l4) {
    const int phys = (l4 ^ row ^ (row >> 2)) & 3;
    return *(const frag_ab*)((const char*)slab + row * 64 + phys * 16);
}

// ---------------- pass 1: x partial stats + transpose to xt[b][p][c] bf16 ----------------
// partials TRANSPOSED: ps/pq[b][c][pblk] so fold reduces contiguously
__global__ __launch_bounds__(256) void transpose_stats_kernel(
    const float* __restrict__ x, u16* __restrict__ xt,
    float* __restrict__ ps, float* __restrict__ pq)
{
    constexpr int PADW = 68;                       // row pitch in u16 (136B)
    __shared__ __align__(16) u16 tile[64 * PADW];  // [px][ch]
    const int b = blockIdx.z, c0 = blockIdx.y * 64, p0 = blockIdx.x * 64;
    const int pblk = blockIdx.x;                   // 0..255
    const int t = threadIdx.x;
    const int lane = t & 63, w = t >> 6;
    const int pq_ = lane & 15, cq = lane >> 4;
    const int quad = w * 4 + cq;                   // ch-quad 0..15
    const float* xb = x + ((size_t)b * NC + c0) * HW + p0;

    float va[4][4];                                // [j=ch][i=px]
    #pragma unroll
    for (int j = 0; j < 4; ++j) {
        const float4 v = *(const float4*)(xb + (size_t)(quad * 4 + j) * HW + pq_ * 4);
        va[j][0] = v.x; va[j][1] = v.y; va[j][2] = v.z; va[j][3] = v.w;
        float s1 = v.x + v.y + v.z + v.w;
        float s2 = v.x*v.x + v.y*v.y + v.z*v.z + v.w*v.w;
        #pragma unroll
        for (int d = 1; d < 16; d <<= 1) {
            s1 += __shfl_xor(s1, d, 64);
            s2 += __shfl_xor(s2, d, 64);
        }
        if (pq_ == 0) {
            const int ch = c0 + quad * 4 + j;
            ps[((size_t)b * NC + ch) * 256 + pblk] = s1;
            pq[((size_t)b * NC + ch) * 256 + pblk] = s2;
        }
    }
    #pragma unroll
    for (int i = 0; i < 4; ++i) {
        alignas(8) u16 pk[4];
        #pragma unroll
        for (int j = 0; j < 4; ++j) pk[j] = bf16bits(va[j][i]);
        *(uint2*)&tile[(pq_ * 4 + i) * PADW + quad * 4] = *(const uint2*)pk;
    }
    __syncthreads();
    const int pl = t >> 2, q = t & 3;
    u16* dst = xt + ((size_t)b * HW + p0 + pl) * NC + c0;
    #pragma unroll
    for (int s = 0; s < 2; ++s) {
        const int ch8 = q + s * 4;
        const uint2 lo = *(const uint2*)&tile[pl * PADW + ch8 * 8];
        const uint2 hi = *(const uint2*)&tile[pl * PADW + ch8 * 8 + 4];
        const uint4 o4 = {lo.x, lo.y, hi.x, hi.y};
        *(uint4*)(dst + ch8 * 8) = o4;
    }
}

// ---------------- fold: reduce partials[b][c][256] -> mu/rs, fold IN into weights/bias ----------------
__global__ __launch_bounds__(256) void fold_kernel(
    const float* __restrict__ w, const float* __restrict__ bias,
    const float* __restrict__ ps, const float* __restrict__ pq,
    u16* __restrict__ we, float* __restrict__ be)
{
    const int b = blockIdx.y, oc = blockIdx.x * 64;
    __shared__ float mu[NC], rs[NC];
    __shared__ __align__(16) float wt[64 * NC];
    const int t = threadIdx.x;
    {
        const float4* pp = (const float4*)(ps + ((size_t)b * NC + t) * 256);
        const float4* qq = (const float4*)(pq + ((size_t)b * NC + t) * 256);
        float s1 = 0.f, s2 = 0.f;
        #pragma unroll 8
        for (int i = 0; i < 64; ++i) {
            const float4 a = pp[i], c = qq[i];
            s1 += a.x + a.y + a.z + a.w;
            s2 += c.x + c.y + c.z + c.w;
        }
        const float m = s1 * (1.0f / HW);
        mu[t] = m;
        rs[t] = rsqrtf(s2 * (1.0f / HW) - m * m + 1e-5f);
    }
    #pragma unroll
    for (int i = 0; i < 16; ++i)
        *(float4*)&wt[i*1024 + t*4] = *(const float4*)&w[(size_t)oc*NC + i*1024 + t*4];
    __syncthreads();
    const int o = oc + (t >> 2), q = t & 3;
    const float* wrow = &wt[(t >> 2) * NC];
    u16* werow = we + ((size_t)b * NC + o) * NC;
    float bacc = 0.f;
    for (int cc = 0; cc < 8; ++cc) {
        alignas(16) u16 pk[8];
        #pragma unroll
        for (int jj = 0; jj < 8; ++jj) {
            const int c = q*64 + cc*8 + jj;
            const float wv = wrow[c];
            bacc -= wv * mu[c] * rs[c];
            pk[jj] = bf16bits(wv * rs[c]);
        }
        *(uint4*)(werow + q*64 + cc*8) = *(const uint4*)pk;
    }
    bacc += __shfl_xor(bacc, 1, 64);
    bacc += __shfl_xor(bacc, 2, 64);
    if (q == 0) be[b*NC + o] = bias[o] + bacc;
}

// ---------------- fused GEMM: r1 structure (64px x 256outs, 4 waves, single-buffer) ----------------
// REP: internal repeat for rocprof observability (idempotent direct stores).
// STAGE1 -> ht[b][p][o] bf16 + h partials [b][o][pblk]; STAGE2 -> out[b][o][p] fp32.
template<int STAGE, int REP>
__global__ __launch_bounds__(256, 4) void gemm_kernel(
    const u16* __restrict__ pixM,   // [B*HW][NC] (xt or ht)
    const u16* __restrict__ wMat,   // [B][NC][NC] folded weights
    const float* __restrict__ biasE,// [B][NC]
    u16* __restrict__ outB,         // stage1: ht
    float* __restrict__ outF,       // stage2: out
    float* __restrict__ hps, float* __restrict__ hpq)
{
    __shared__ __align__(16) u16 ldsS[64 * 32];    // pixel slab 4 KB
    __shared__ __align__(16) u16 ldsB[256 * 32];   // weight slab 16 KB

    // XCD-bijective remap: each XCD gets 512 consecutive logical blocks = 2 whole batches
    const int lin = blockIdx.y * gridDim.x + blockIdx.x;     // 0..4095
    const int nl  = (lin & 7) * 512 + (lin >> 3);
    const int b = nl >> 8, pblk = nl & 255;
    const int p0 = pblk * 64;

    const int tid = threadIdx.x;
    const int lane = tid & 63, wid = tid >> 6;     // 4 waves; wave owns outs [wid*64, wid*64+64)
    const int l15 = lane & 15, l4 = lane >> 4;

    const u16* gP = pixM + ((size_t)b * HW + p0) * NC;
    const u16* gW = wMat + (size_t)b * NC * NC;

    const int rin  = lane >> 2;
    const int ssrc = ((lane & 3) ^ ((lane >> 2) & 3) ^ ((lane >> 4) & 3));  // row-invariant (j*16 == 0 mod 4 groups)

    for (int rep = 0; rep < REP; ++rep) {
        f32x4 acc[4][4];
        #pragma unroll
        for (int i = 0; i < 4; ++i)
            #pragma unroll
            for (int j = 0; j < 4; ++j)
                acc[i][j] = (f32x4){0.f, 0.f, 0.f, 0.f};

        for (int ks = 0; ks < 8; ++ks) {
            const int k0 = ks * 32;
            #pragma unroll
            for (int j = wid; j < 20; j += 4) {
                if (j < 16) {
                    const int row = j * 16 + rin;
                    gload16(gW + (size_t)row * NC + k0 + ssrc * 8, (char*)ldsB + j * 1024);
                } else {
                    const int row = (j - 16) * 16 + rin;
                    gload16(gP + (size_t)row * NC + k0 + ssrc * 8, (char*)ldsS + (j - 16) * 1024);
                }
            }
            __syncthreads();

            const u16* sA; const u16* sB; int aOff, bOff;
            if constexpr (STAGE == 1) { sA = ldsS; aOff = 0;        sB = ldsB; bOff = wid * 64; }
            else                      { sA = ldsB; aOff = wid * 64; sB = ldsS; bOff = 0; }

            frag_ab a[4];
            #pragma unroll
            for (int mi = 0; mi < 4; ++mi)
                a[mi] = read_frag(sA, aOff + 16*mi + l15, l4);
            #pragma unroll
            for (int ni = 0; ni < 4; ++ni) {
                const frag_ab bfr = read_frag(sB, bOff + 16*ni + l15, l4);
                #pragma unroll
                for (int mi = 0; mi < 4; ++mi)
                    acc[mi][ni] = __builtin_amdgcn_mfma_f32_16x16x32_bf16(a[mi], bfr, acc[mi][ni], 0, 0, 0);
            }
            __syncthreads();
        }

        if constexpr (STAGE == 1) {
            // acc rows = pixels, cols = outs (wid*64 + 16ni + l15)
            u16* htp = outB + ((size_t)b * HW + p0) * NC + wid * 64;
            float s1[4] = {0.f,0.f,0.f,0.f}, s2[4] = {0.f,0.f,0.f,0.f};
            #pragma unroll
            for (int ni = 0; ni < 4; ++ni) {
                const float bn = biasE[b*NC + wid*64 + 16*ni + l15];
                #pragma unroll
                for (int mi = 0; mi < 4; ++mi) {
                    #pragma unroll
                    for (int r = 0; r < 4; ++r) {
                        const float v = fmaxf(acc[mi][ni][r] + bn, 0.f);
                        s1[ni] += v; s2[ni] += v * v;
                        htp[(size_t)(16*mi + l4*4 + r) * NC + 16*ni + l15] = bf16bits(v);
                    }
                }
            }
            #pragma unroll
            for (int ni = 0; ni < 4; ++ni) {
                float a1 = s1[ni], a2 = s2[ni];
                a1 += __shfl_xor(a1, 16, 64); a1 += __shfl_xor(a1, 32, 64);
                a2 += __shfl_xor(a2, 16, 64); a2 += __shfl_xor(a2, 32, 64);
                if (l4 == 0) {
                    const int col = wid*64 + 16*ni + l15;
                    hps[((size_t)b * NC + col) * 256 + pblk] = a1;
                    hpq[((size_t)b * NC + col) * 256 + pblk] = a2;
                }
            }
        } else {
            // acc rows = outs (wid*64 + 16mi + l4*4 + r), cols = pixels -> native NCHW
            float* op = outF + ((size_t)b * NC + wid * 64) * HW + p0;
            #pragma unroll
            for (int mi = 0; mi < 4; ++mi) {
                #pragma unroll
                for (int r = 0; r < 4; ++r) {
                    const int orow = 16*mi + l4*4 + r;
                    const float bm = biasE[b*NC + wid*64 + orow];
                    #pragma unroll
                    for (int ni = 0; ni < 4; ++ni)
                        op[(size_t)orow * HW + 16*ni + l15] = fmaxf(acc[mi][ni][r] + bm, 0.f);
                }
            }
        }
        __syncthreads();   // quiesce before next rep re-stages LDS
    }
}

extern "C" void kernel_launch(void* const* d_in, const int* in_sizes, int n_in,
                              void* d_out, int out_size, void* d_ws, size_t ws_size,
                              hipStream_t stream)
{
    (void)in_sizes; (void)n_in; (void)out_size;
    const float* x  = (const float*)d_in[0];
    const float* w1 = (const float*)d_in[1];
    const float* b1 = (const float*)d_in[2];
    const float* w2 = (const float*)d_in[3];
    const float* b2 = (const float*)d_in[4];
    float* out = (float*)d_out;

    // scratch carved out of d_out (268 MB): dead before gemm<2> overwrites it
    char* od = (char*)d_out;
    u16*   xt  = (u16*)od;                        // 134,217,728 B
    float* xps = (float*)(od + 134217728);        //   4,194,304 (16*256*256 f32)
    float* xpq = (float*)(od + 138412032);        //   4,194,304
    float* hps = (float*)(od + 142606336);        //   4,194,304
    float* hpq = (float*)(od + 146800640);        //   4,194,304

    char* ws = (char*)d_ws;
    const size_t NEED = 138444800;
    if (ws_size < NEED) return;
    u16*   ht  = (u16*)(ws);                      // 134,217,728
    u16*   w1e = (u16*)(ws + 134217728);          //   2,097,152
    u16*   w2e = (u16*)(ws + 136314880);          //   2,097,152
    float* b1e = (float*)(ws + 138412032);        //      16,384
    float* b2e = (float*)(ws + 138428416);        //      16,384

    transpose_stats_kernel<<<dim3(HW/64, NC/64, 16), 256, 0, stream>>>(x, xt, xps, xpq);
    fold_kernel<<<dim3(4, 16), 256, 0, stream>>>(w1, b1, xps, xpq, w1e, b1e);
    gemm_kernel<1, 2><<<dim3(HW/64, 16), 256, 0, stream>>>(xt, w1e, b1e, ht, nullptr, hps, hpq);
    fold_kernel<<<dim3(4, 16), 256, 0, stream>>>(w2, b2, hps, hpq, w2e, b2e);
    gemm_kernel<2, 2><<<dim3(HW/64, 16), 256, 0, stream>>>(ht, w2e, b2e, nullptr, out, nullptr, nullptr);
}

// Round 6
// 315.846 us; speedup vs baseline: 5.1780x; 5.1780x over previous
//
#include <hip/hip_runtime.h>
#include <hip/hip_bf16.h>
#include <cstdint>
#include <cstddef>

#define DEVI __device__ __forceinline__

typedef unsigned short u16;
using frag_ab = __attribute__((ext_vector_type(8))) short;   // 8 bf16 (4 VGPRs)
using f32x4   = __attribute__((ext_vector_type(4))) float;   // mfma acc

constexpr int HW = 16384;   // 128*128 spatial
constexpr int NC = 256;     // channels (Cin = Cout = 256)

DEVI u16 bf16bits(float f) {
    union { float f; uint32_t u; } cv; cv.f = f;
    uint32_t u = cv.u;
    u += 0x7fffu + ((u >> 16) & 1u);   // RNE
    return (u16)(u >> 16);
}

DEVI void gload16(const void* g, void* l) {
    __builtin_amdgcn_global_load_lds(
        (const __attribute__((address_space(1))) uint32_t*)g,
        (__attribute__((address_space(3))) uint32_t*)l, 16, 0, 0);
}

// LDS slab: [row][64B]; 16B slot s at phys slot s ^ (row&3) ^ ((row>>2)&3).
// Staging fetches pre-swizzled global slot (m173); frag reads use matching phys.
DEVI frag_ab read_frag(const u16* slab, int row, int l4) {
    const int phys = (l4 ^ row ^ (row >> 2)) & 3;
    return *(const frag_ab*)((const char*)slab + row * 64 + phys * 16);
}

// ---------------- pass 1: x partial stats + transpose to xt[b][p][c] bf16 ----------------
// partials ps/pq[b][pblk][c]: full-sector float4 stores, fold reduces coalesced over pblk
__global__ __launch_bounds__(256) void transpose_stats_kernel(
    const float* __restrict__ x, u16* __restrict__ xt,
    float* __restrict__ ps, float* __restrict__ pq)
{
    constexpr int PADW = 68;                       // row pitch in u16 (136B)
    __shared__ __align__(16) u16 tile[64 * PADW];  // [px][ch]
    const int b = blockIdx.z, c0 = blockIdx.y * 64, p0 = blockIdx.x * 64;
    const int pblk = blockIdx.x;                   // 0..255
    const int t = threadIdx.x;
    const int lane = t & 63, w = t >> 6;
    const int pq_ = lane & 15, cq = lane >> 4;
    const int quad = w * 4 + cq;                   // ch-quad 0..15
    const float* xb = x + ((size_t)b * NC + c0) * HW + p0;

    float va[4][4];                                // [j=ch][i=px]
    float aS[4], aQ[4];
    #pragma unroll
    for (int j = 0; j < 4; ++j) {
        const float4 v = *(const float4*)(xb + (size_t)(quad * 4 + j) * HW + pq_ * 4);
        va[j][0] = v.x; va[j][1] = v.y; va[j][2] = v.z; va[j][3] = v.w;
        float s1 = v.x + v.y + v.z + v.w;
        float s2 = v.x*v.x + v.y*v.y + v.z*v.z + v.w*v.w;
        #pragma unroll
        for (int d = 1; d < 16; d <<= 1) {
            s1 += __shfl_xor(s1, d, 64);
            s2 += __shfl_xor(s2, d, 64);
        }
        aS[j] = s1; aQ[j] = s2;
    }
    if (pq_ == 0) {                                // lanes 0,16,32,48: one 16B store each
        const float4 vs = {aS[0], aS[1], aS[2], aS[3]};
        const float4 vq = {aQ[0], aQ[1], aQ[2], aQ[3]};
        *(float4*)&ps[((size_t)b * 256 + pblk) * NC + c0 + quad * 4] = vs;
        *(float4*)&pq[((size_t)b * 256 + pblk) * NC + c0 + quad * 4] = vq;
    }
    #pragma unroll
    for (int i = 0; i < 4; ++i) {
        alignas(8) u16 pk[4];
        #pragma unroll
        for (int j = 0; j < 4; ++j) pk[j] = bf16bits(va[j][i]);
        *(uint2*)&tile[(pq_ * 4 + i) * PADW + quad * 4] = *(const uint2*)pk;
    }
    __syncthreads();
    const int pl = t >> 2, q = t & 3;
    u16* dst = xt + ((size_t)b * HW + p0 + pl) * NC + c0;
    #pragma unroll
    for (int s = 0; s < 2; ++s) {
        const int ch8 = q + s * 4;
        const uint2 lo = *(const uint2*)&tile[pl * PADW + ch8 * 8];
        const uint2 hi = *(const uint2*)&tile[pl * PADW + ch8 * 8 + 4];
        const uint4 o4 = {lo.x, lo.y, hi.x, hi.y};
        *(uint4*)(dst + ch8 * 8) = o4;
    }
}

// ---------------- fold: reduce partials[b][256][c] -> mu/rs, fold IN into weights/bias ----------------
__global__ __launch_bounds__(256) void fold_kernel(
    const float* __restrict__ w, const float* __restrict__ bias,
    const float* __restrict__ ps, const float* __restrict__ pq,
    u16* __restrict__ we, float* __restrict__ be)
{
    const int b = blockIdx.y, oc = blockIdx.x * 64;
    __shared__ float mu[NC], rs[NC];
    __shared__ __align__(16) float wt[64 * NC];
    const int t = threadIdx.x;
    {
        float s1 = 0.f, s2 = 0.f;
        const float* pp = ps + (size_t)b * 256 * NC + t;    // [i][t], coalesced across threads
        const float* qq = pq + (size_t)b * 256 * NC + t;
        for (int i = 0; i < 256; ++i) {
            s1 += pp[(size_t)i * NC];
            s2 += qq[(size_t)i * NC];
        }
        const float m = s1 * (1.0f / HW);
        mu[t] = m;
        rs[t] = rsqrtf(s2 * (1.0f / HW) - m * m + 1e-5f);
    }
    #pragma unroll
    for (int i = 0; i < 16; ++i)
        *(float4*)&wt[i*1024 + t*4] = *(const float4*)&w[(size_t)oc*NC + i*1024 + t*4];
    __syncthreads();
    const int o = oc + (t >> 2), q = t & 3;
    const float* wrow = &wt[(t >> 2) * NC];
    u16* werow = we + ((size_t)b * NC + o) * NC;
    float bacc = 0.f;
    for (int cc = 0; cc < 8; ++cc) {
        alignas(16) u16 pk[8];
        #pragma unroll
        for (int jj = 0; jj < 8; ++jj) {
            const int c = q*64 + cc*8 + jj;
            const float wv = wrow[c];
            bacc -= wv * mu[c] * rs[c];
            pk[jj] = bf16bits(wv * rs[c]);
        }
        *(uint4*)(werow + q*64 + cc*8) = *(const uint4*)pk;
    }
    bacc += __shfl_xor(bacc, 1, 64);
    bacc += __shfl_xor(bacc, 2, 64);
    if (q == 0) be[b*NC + o] = bias[o] + bacc;
}

// ---------------- fused GEMM: pixel-burst pipeline ----------------
// 64 px x 256 outs per block, 4 waves. Prologue bursts the FULL-K pixel strip (32 KB)
// + W slab 0; k-loop double-buffers W slabs with prefetch-1; raw s_barrier + asm vmcnt
// (no __syncthreads -> no forced drain beyond what's needed). 64 KB LDS -> 2 blocks/CU,
// ~96 KB in flight per CU at burst time (vs 1.3 KB in the r5 structure).
// STAGE1 -> ht[b][p][o] bf16 + h partials [b][pblk][o]; STAGE2 -> out[b][o][p] fp32.
template<int STAGE>
__global__ __launch_bounds__(256, 2) void gemm_kernel(
    const u16* __restrict__ pixM,   // [B*HW][NC] (xt or ht)
    const u16* __restrict__ wMat,   // [B][NC][NC] folded weights
    const float* __restrict__ biasE,// [B][NC]
    u16* __restrict__ outB,         // stage1: ht
    float* __restrict__ outF,       // stage2: out
    float* __restrict__ hps, float* __restrict__ hpq)
{
    __shared__ __align__(16) u16 ldsP[8 * 64 * 32];   // 32 KB: 8 k-slices of [64 rows][32 k]
    __shared__ __align__(16) u16 ldsW[2][256 * 32];   // 2 x 16 KB weight slabs

    const int b = blockIdx.y, pblk = blockIdx.x;
    const int p0 = pblk * 64;
    const int tid = threadIdx.x;
    const int lane = tid & 63, wid = tid >> 6;        // 4 waves; wave owns outs [wid*64, +64)
    const int l15 = lane & 15, l4 = lane >> 4;

    const u16* gP = pixM + ((size_t)b * HW + p0) * NC;
    const u16* gW = wMat + (size_t)b * NC * NC;

    const int rin  = lane >> 2;
    const int prow = wid * 16 + rin;                  // pixel row 0..63
    const int psl  = ((lane & 3) ^ prow ^ (prow >> 2)) & 3;
    int wrowq[4], wslq[4];
    #pragma unroll
    for (int q = 0; q < 4; ++q) {
        wrowq[q] = wid * 64 + q * 16 + rin;           // weight rows 0..255
        wslq[q]  = ((lane & 3) ^ wrowq[q] ^ (wrowq[q] >> 2)) & 3;
    }

    // ---- prologue burst: all 8 pixel k-slices + W slab 0 (12 gload16/thread in flight)
    #pragma unroll
    for (int ks = 0; ks < 8; ++ks)
        gload16(gP + (size_t)prow * NC + ks * 32 + psl * 8,
                (char*)ldsP + ks * 4096 + wid * 1024);
    #pragma unroll
    for (int q = 0; q < 4; ++q)
        gload16(gW + (size_t)wrowq[q] * NC + wslq[q] * 8,
                (char*)ldsW[0] + (wid * 4 + q) * 1024);

    f32x4 acc[4][4];
    #pragma unroll
    for (int i = 0; i < 4; ++i)
        #pragma unroll
        for (int j = 0; j < 4; ++j)
            acc[i][j] = (f32x4){0.f, 0.f, 0.f, 0.f};

    for (int ks = 0; ks < 8; ++ks) {
        asm volatile("s_waitcnt vmcnt(0)" ::: "memory");   // W_ks (+ at ks=0, the pixel burst)
        __builtin_amdgcn_s_barrier();

        const u16* wslab = ldsW[ks & 1];
        const u16* pslab = ldsP + ks * 2048;               // 4096 B = 2048 u16

        const u16* sA; const u16* sB; int aOff, bOff;
        if constexpr (STAGE == 1) { sA = pslab; aOff = 0;        sB = wslab; bOff = wid * 64; }
        else                      { sA = wslab; aOff = wid * 64; sB = pslab; bOff = 0; }

        frag_ab a[4], bf[4];
        #pragma unroll
        for (int mi = 0; mi < 4; ++mi)
            a[mi] = read_frag(sA, aOff + 16*mi + l15, l4);
        #pragma unroll
        for (int ni = 0; ni < 4; ++ni)
            bf[ni] = read_frag(sB, bOff + 16*ni + l15, l4);

        if (ks < 7) {                                      // prefetch W_{ks+1} into other buf
            const int k0 = (ks + 1) * 32;                  // (safe: that buf's readers passed
            #pragma unroll                                 //  the barrier above)
            for (int q = 0; q < 4; ++q)
                gload16(gW + (size_t)wrowq[q] * NC + k0 + wslq[q] * 8,
                        (char*)ldsW[(ks + 1) & 1] + (wid * 4 + q) * 1024);
        }

        #pragma unroll
        for (int ni = 0; ni < 4; ++ni)
            #pragma unroll
            for (int mi = 0; mi < 4; ++mi)
                acc[mi][ni] = __builtin_amdgcn_mfma_f32_16x16x32_bf16(a[mi], bf[ni], acc[mi][ni], 0, 0, 0);
    }

    if constexpr (STAGE == 1) {
        // acc rows = pixels (16mi + l4*4 + r), cols = outs (wid*64 + 16ni + l15)
        u16* htp = outB + ((size_t)b * HW + p0) * NC + wid * 64;
        float s1[4] = {0.f,0.f,0.f,0.f}, s2[4] = {0.f,0.f,0.f,0.f};
        #pragma unroll
        for (int ni = 0; ni < 4; ++ni) {
            const float bn = biasE[b*NC + wid*64 + 16*ni + l15];
            #pragma unroll
            for (int mi = 0; mi < 4; ++mi) {
                #pragma unroll
                for (int r = 0; r < 4; ++r) {
                    const float v = fmaxf(acc[mi][ni][r] + bn, 0.f);
                    s1[ni] += v; s2[ni] += v * v;
                    htp[(size_t)(16*mi + l4*4 + r) * NC + 16*ni + l15] = bf16bits(v);
                }
            }
        }
        #pragma unroll
        for (int ni = 0; ni < 4; ++ni) {
            float a1 = s1[ni], a2 = s2[ni];
            a1 += __shfl_xor(a1, 16, 64); a1 += __shfl_xor(a1, 32, 64);
            a2 += __shfl_xor(a2, 16, 64); a2 += __shfl_xor(a2, 32, 64);
            if (l4 == 0) {                                 // 16 lanes x 4B = full 64B sector
                const int col = wid*64 + 16*ni + l15;
                hps[((size_t)b * 256 + pblk) * NC + col] = a1;
                hpq[((size_t)b * 256 + pblk) * NC + col] = a2;
            }
        }
    } else {
        // acc rows = outs (wid*64 + 16mi + l4*4 + r), cols = pixels -> native NCHW
        float* op = outF + ((size_t)b * NC + wid * 64) * HW + p0;
        #pragma unroll
        for (int mi = 0; mi < 4; ++mi) {
            #pragma unroll
            for (int r = 0; r < 4; ++r) {
                const int orow = 16*mi + l4*4 + r;
                const float bm = biasE[b*NC + wid*64 + orow];
                #pragma unroll
                for (int ni = 0; ni < 4; ++ni)
                    op[(size_t)orow * HW + 16*ni + l15] = fmaxf(acc[mi][ni][r] + bm, 0.f);
            }
        }
    }
}

extern "C" void kernel_launch(void* const* d_in, const int* in_sizes, int n_in,
                              void* d_out, int out_size, void* d_ws, size_t ws_size,
                              hipStream_t stream)
{
    (void)in_sizes; (void)n_in; (void)out_size;
    const float* x  = (const float*)d_in[0];
    const float* w1 = (const float*)d_in[1];
    const float* b1 = (const float*)d_in[2];
    const float* w2 = (const float*)d_in[3];
    const float* b2 = (const float*)d_in[4];
    float* out = (float*)d_out;

    // scratch carved out of d_out (268 MB): dead before gemm<2> overwrites it
    char* od = (char*)d_out;
    u16*   xt  = (u16*)od;                        // 134,217,728 B
    float* xps = (float*)(od + 134217728);        //   4,194,304 (16*256*256 f32)
    float* xpq = (float*)(od + 138412032);        //   4,194,304
    float* hps = (float*)(od + 142606336);        //   4,194,304
    float* hpq = (float*)(od + 146800640);        //   4,194,304

    char* ws = (char*)d_ws;
    const size_t NEED = 138444800;
    if (ws_size < NEED) return;
    u16*   ht  = (u16*)(ws);                      // 134,217,728
    u16*   w1e = (u16*)(ws + 134217728);          //   2,097,152
    u16*   w2e = (u16*)(ws + 136314880);          //   2,097,152
    float* b1e = (float*)(ws + 138412032);        //      16,384
    float* b2e = (float*)(ws + 138428416);        //      16,384

    transpose_stats_kernel<<<dim3(HW/64, NC/64, 16), 256, 0, stream>>>(x, xt, xps, xpq);
    fold_kernel<<<dim3(4, 16), 256, 0, stream>>>(w1, b1, xps, xpq, w1e, b1e);
    gemm_kernel<1><<<dim3(HW/64, 16), 256, 0, stream>>>(xt, w1e, b1e, ht, nullptr, hps, hpq);
    fold_kernel<<<dim3(4, 16), 256, 0, stream>>>(w2, b2, hps, hpq, w2e, b2e);
    gemm_kernel<2><<<dim3(HW/64, 16), 256, 0, stream>>>(ht, w2e, b2e, nullptr, out, nullptr, nullptr);
}